// Round 1
// 547.628 us; speedup vs baseline: 1.0356x; 1.0356x over previous
//
#include <hip/hip_runtime.h>

// Problem constants (match reference)
#define OUT_F 4096   // M
#define IN_F  4096   // K
#define NCOLS 8192   // N

#define GM OUT_F
#define GK IN_F
#define GN NCOLS

typedef __attribute__((ext_vector_type(8))) short short8;
typedef __attribute__((ext_vector_type(4))) float f32x4;

// ---------------------------------------------------------------------------
// helpers
// ---------------------------------------------------------------------------
__device__ inline unsigned short f2bf(float f) {
    union { float f; unsigned u; } c; c.f = f;
    unsigned u = c.u;
    u += 0x7fffu + ((u >> 16) & 1u);   // round-to-nearest-even
    return (unsigned short)(u >> 16);
}

__device__ inline void gll16(const void* g, void* l) {
    __builtin_amdgcn_global_load_lds(
        (const __attribute__((address_space(1))) unsigned int*)g,
        (__attribute__((address_space(3))) unsigned int*)l, 16, 0, 0);
}

// ---------------------------------------------------------------------------
// Densify path
// ---------------------------------------------------------------------------
__global__ void scatter_dense(const int* __restrict__ rows, const int* __restrict__ cols,
                              const float* __restrict__ vals, float* __restrict__ W, int nnz) {
    int i = blockIdx.x * blockDim.x + threadIdx.x;
    if (i < nnz) atomicAdd(&W[(size_t)rows[i] * IN_F + cols[i]], vals[i]);
}

__global__ void convert_w(const float* __restrict__ Wf, unsigned short* __restrict__ Wb) {
    int i = blockIdx.x * blockDim.x + threadIdx.x;  // over elems/4
    float4 v = ((const float4*)Wf)[i];
    ushort4 o;
    o.x = f2bf(v.x); o.y = f2bf(v.y); o.z = f2bf(v.z); o.w = f2bf(v.w);
    ((ushort4*)Wb)[i] = o;
}

// x [IN_F][NCOLS] f32 -> xT [NCOLS][IN_F] bf16, 64x64 tiles via LDS
__global__ __launch_bounds__(256) void transpose_x(const float* __restrict__ x,
                                                   unsigned short* __restrict__ xT) {
    __shared__ float tile[64][65];
    const int k0 = blockIdx.x * 64;   // x row block (K dim)
    const int n0 = blockIdx.y * 64;   // x col block (N dim)
    const int t = threadIdx.x;
    const int c4 = (t & 15) * 4;
    const int r0 = t >> 4;            // 0..15
    for (int p = 0; p < 4; ++p) {
        int r = r0 + p * 16;
        float4 v = *(const float4*)&x[(size_t)(k0 + r) * NCOLS + n0 + c4];
        tile[r][c4 + 0] = v.x; tile[r][c4 + 1] = v.y;
        tile[r][c4 + 2] = v.z; tile[r][c4 + 3] = v.w;
    }
    __syncthreads();
    const int n  = t >> 2;            // 0..63
    const int ks = (t & 3) * 16;      // 0,16,32,48
    unsigned w[8];
    for (int m = 0; m < 8; ++m) {
        unsigned short lo = f2bf(tile[ks + 2 * m + 0][n]);
        unsigned short hi = f2bf(tile[ks + 2 * m + 1][n]);
        w[m] = (unsigned)lo | ((unsigned)hi << 16);
    }
    uint4* dst = (uint4*)&xT[(size_t)(n0 + n) * GK + k0 + ks];
    dst[0] = make_uint4(w[0], w[1], w[2], w[3]);
    dst[1] = make_uint4(w[4], w[5], w[6], w[7]);
}

// ---------------------------------------------------------------------------
// GEMM: C[GM][GN] f32 = A(bf16 [GM][GK]) * B, with B given as BT bf16 [GN][GK].
// 256x256 8-phase schedule (T1+T2+T3+T4+T5, guide §5 template):
//   512 thr = 8 waves (2M x 4N), per-wave output 128x64, BK=64 (2 K-halves of 32).
//   LDS = 8 half-slots of 16 KiB: [buf(2)][op(2)][khalf(2)] x (256 rows x 32k bf16).
//   Per phase: {4-or-8 ds_read_b128 | stage 1 half-slot (2x global_load_lds w16) |
//               s_barrier | setprio(1) 16x MFMA setprio(0) | [vmcnt(8)] s_barrier}.
//   vmcnt(8) only at even phase ends: 6 half-slots (12 loads) max outstanding,
//   each wait retires the 2 oldest half-slots = exactly what the next odd phase reads.
//   Swizzle: 64B row of 4x16B blocks; logical block j of row r lives at slot j^(r&3).
//   Stage pre-swizzles the GLOBAL source (LDS dest stays linear, rule #21);
//   fragment ds_read applies the same involution -> 2-way bank aliasing only (free).
// ---------------------------------------------------------------------------
__global__ __launch_bounds__(512, 2) void gemm256(const unsigned short* __restrict__ A,
                                                  const unsigned short* __restrict__ BT,
                                                  float* __restrict__ C) {
    __shared__ unsigned short lds[8 * 8192];   // 128 KiB

    const int tid  = threadIdx.x;
    const int wave = tid >> 6;
    const int lane = tid & 63;

    // XCD-aware bijective swizzle (nwg = 512, 512 % 8 == 0)
    const int wg  = blockIdx.y * 32 + blockIdx.x;
    const int swz = (wg & 7) * 64 + (wg >> 3);
    const int m0  = (swz >> 5) * 256;
    const int n0  = (swz & 31) * 256;

    const int wm = wave >> 2;          // 0..1  (M half of tile)
    const int wn = wave & 3;           // 0..3  (N quarter of tile)

    // staging mapping: chunk c = q*512 + tid; row r = c>>2 (0..255), slot s = c&3.
    // lane fetches global k-block s^(r&3) so linear LDS slot s holds swizzled data.
    const int r0s  = tid >> 2;                       // 0..127 (q=0), +128 for q=1
    const int swz0 = ((tid & 3) ^ (r0s & 3)) << 3;   // elems
    const unsigned short* pA0 = A  + (size_t)(m0 + r0s) * GK + swz0;
    const unsigned short* pA1 = pA0 + (size_t)128 * GK;
    const unsigned short* pB0 = BT + (size_t)(n0 + r0s) * GK + swz0;
    const unsigned short* pB1 = pB0 + (size_t)128 * GK;

    // fragment mapping for 16x16x32: row = 16*frag + frow, k-block = lane>>4
    const int frow  = lane & 15;
    const int ajb   = ((lane >> 4) ^ (frow & 3)) << 3;          // swizzled 8-elem block
    const int abase = ((wm << 7) + frow) * 32 + ajb;            // A region elem offset
    const int bbase = ((wn << 6) + frow) * 32 + ajb;            // B region elem offset

    f32x4 acc[8][4] = {};

#define STAGE_A(bufc, khc, kt_) do {                                            \
        const int koA_ = ((((kt_) & 63) << 6) + ((khc) << 5));                  \
        gll16(pA0 + koA_, &lds[(((bufc) << 2) + (khc)) * 8192 + (wave << 9)]);  \
        gll16(pA1 + koA_, &lds[(((bufc) << 2) + (khc)) * 8192 + 4096 + (wave << 9)]); \
    } while (0)

#define STAGE_B(bufc, khc, kt_) do {                                            \
        const int koB_ = ((((kt_) & 63) << 6) + ((khc) << 5));                  \
        gll16(pB0 + koB_, &lds[(((bufc) << 2) + 2 + (khc)) * 8192 + (wave << 9)]); \
        gll16(pB1 + koB_, &lds[(((bufc) << 2) + 2 + (khc)) * 8192 + 4096 + (wave << 9)]); \
    } while (0)

    // prologue: stage kt0 fully + kt1 khalf0  (= steady-state S3..S8 pattern)
    STAGE_A(0, 0, 0); STAGE_B(0, 0, 0);
    STAGE_A(0, 1, 0); STAGE_B(0, 1, 0);
    STAGE_A(1, 0, 1); STAGE_B(1, 0, 1);
    asm volatile("s_waitcnt vmcnt(8)" ::: "memory");   // oldest 2 half-slots resident
    __builtin_amdgcn_s_barrier();

// One K-half = 2 phases (mh0, mh1). bf reused across both (8/4 ds_read pattern).
// vmcnt(8) at the pair end retires the 2 oldest in-flight half-slots.
#define KHALF_BLOCK(bufc, khc, STAGE1, STAGE2) do {                             \
        const unsigned short* Ar_ = &lds[(((bufc) << 2) + (khc)) * 8192];       \
        const unsigned short* Br_ = &lds[(((bufc) << 2) + 2 + (khc)) * 8192];   \
        short8 af[4], bf[4];                                                    \
        _Pragma("unroll")                                                       \
        for (int nj = 0; nj < 4; ++nj) bf[nj] = *(const short8*)&Br_[bbase + nj * 512]; \
        _Pragma("unroll")                                                       \
        for (int mi = 0; mi < 4; ++mi) af[mi] = *(const short8*)&Ar_[abase + mi * 512]; \
        STAGE1;                                                                 \
        __builtin_amdgcn_s_barrier();                                           \
        __builtin_amdgcn_s_setprio(1);                                          \
        _Pragma("unroll")                                                       \
        for (int mi = 0; mi < 4; ++mi)                                          \
            _Pragma("unroll")                                                   \
            for (int nj = 0; nj < 4; ++nj)                                      \
                acc[mi][nj] = __builtin_amdgcn_mfma_f32_16x16x32_bf16(          \
                    af[mi], bf[nj], acc[mi][nj], 0, 0, 0);                      \
        __builtin_amdgcn_s_setprio(0);                                          \
        __builtin_amdgcn_s_barrier();                                           \
        _Pragma("unroll")                                                       \
        for (int mi = 0; mi < 4; ++mi) af[mi] = *(const short8*)&Ar_[abase + (4 + mi) * 512]; \
        STAGE2;                                                                 \
        __builtin_amdgcn_s_barrier();                                           \
        __builtin_amdgcn_s_setprio(1);                                          \
        _Pragma("unroll")                                                       \
        for (int mi = 0; mi < 4; ++mi)                                          \
            _Pragma("unroll")                                                   \
            for (int nj = 0; nj < 4; ++nj)                                      \
                acc[4 + mi][nj] = __builtin_amdgcn_mfma_f32_16x16x32_bf16(      \
                    af[mi], bf[nj], acc[4 + mi][nj], 0, 0, 0);                  \
        __builtin_amdgcn_s_setprio(0);                                          \
        asm volatile("s_waitcnt vmcnt(8)" ::: "memory");                        \
        __builtin_amdgcn_s_barrier();                                           \
    } while (0)

#pragma unroll 1
    for (int it = 0; it < GK / 128; ++it) {
        const int kt = it * 2;
        // P1/P2: compute buf0.kh0, stage buf1.kh1 <- kt+1 (freed prev P7/P8)
        KHALF_BLOCK(0, 0, STAGE_A(1, 1, kt + 1), STAGE_B(1, 1, kt + 1));
        // P3/P4: compute buf0.kh1, stage buf0.kh0 <- kt+2 (freed at P2)
        KHALF_BLOCK(0, 1, STAGE_A(0, 0, kt + 2), STAGE_B(0, 0, kt + 2));
        // P5/P6: compute buf1.kh0, stage buf0.kh1 <- kt+2 (freed at P4)
        KHALF_BLOCK(1, 0, STAGE_A(0, 1, kt + 2), STAGE_B(0, 1, kt + 2));
        // P7/P8: compute buf1.kh1, stage buf1.kh0 <- kt+3 (freed at P6)
        KHALF_BLOCK(1, 1, STAGE_A(1, 0, kt + 3), STAGE_B(1, 0, kt + 3));
    }
#undef KHALF_BLOCK
#undef STAGE_A
#undef STAGE_B

    // epilogue: C/D layout col=lane&15, row=(lane>>4)*4+reg
    for (int mi = 0; mi < 8; ++mi) {
        const int r0w = m0 + wm * 128 + mi * 16 + (lane >> 4) * 4;
        for (int nj = 0; nj < 4; ++nj) {
            const int cc = n0 + wn * 64 + nj * 16 + frow;
            for (int r = 0; r < 4; ++r)
                C[(size_t)(r0w + r) * GN + cc] = acc[mi][nj][r];
        }
    }
}

// ---------------------------------------------------------------------------
// Fallback SpMM path (round-1 kernel) if workspace is too small for densify
// ---------------------------------------------------------------------------
#define WS_COUNTS  0
#define WS_OFFSETS 4097
#define WS_CURSOR  8194
#define WS_HEADER  12290

__global__ void hist_kernel(const int* __restrict__ rows, int* __restrict__ counts, int nnz) {
    int i = blockIdx.x * blockDim.x + threadIdx.x;
    if (i < nnz) atomicAdd(&counts[rows[i]], 1);
}

__global__ void scan_kernel(const int* __restrict__ counts, int* __restrict__ offsets) {
    __shared__ int lsum[256];
    int t = threadIdx.x;
    int base = t * 16;
    int local[16];
    int s = 0;
    for (int i = 0; i < 16; ++i) { local[i] = counts[base + i]; s += local[i]; }
    lsum[t] = s;
    __syncthreads();
    if (t == 0) {
        int acc = 0;
        for (int i = 0; i < 256; ++i) { int v = lsum[i]; lsum[i] = acc; acc += v; }
        offsets[OUT_F] = acc;
    }
    __syncthreads();
    int acc = lsum[t];
    for (int i = 0; i < 16; ++i) { offsets[base + i] = acc; acc += local[i]; }
}

__global__ void scatter_kernel(const int* __restrict__ rows, const int* __restrict__ cols,
                               const float* __restrict__ vals,
                               const int* __restrict__ offsets, int* __restrict__ cursor,
                               int* __restrict__ cols_s, float* __restrict__ vals_s, int nnz) {
    int i = blockIdx.x * blockDim.x + threadIdx.x;
    if (i < nnz) {
        int r = rows[i];
        int pos = offsets[r] + atomicAdd(&cursor[r], 1);
        cols_s[pos] = cols[i];
        vals_s[pos] = vals[i];
    }
}

__global__ __launch_bounds__(256) void spmm_kernel(const int* __restrict__ offsets,
                                                   const int* __restrict__ cols_s,
                                                   const float* __restrict__ vals_s,
                                                   const float* __restrict__ x,
                                                   float* __restrict__ out) {
    const int row  = blockIdx.x;
    const int col0 = blockIdx.y * 1024 + threadIdx.x * 4;
    const int k0 = offsets[row];
    const int k1 = offsets[row + 1];
    float4 acc = make_float4(0.f, 0.f, 0.f, 0.f);
    for (int k = k0; k < k1; ++k) {
        const int   c = cols_s[k];
        const float v = vals_s[k];
        const float4 xv = *reinterpret_cast<const float4*>(x + (size_t)c * NCOLS + col0);
        acc.x += v * xv.x;
        acc.y += v * xv.y;
        acc.z += v * xv.z;
        acc.w += v * xv.w;
    }
    *reinterpret_cast<float4*>(out + (size_t)row * NCOLS + col0) = acc;
}

// ---------------------------------------------------------------------------
extern "C" void kernel_launch(void* const* d_in, const int* in_sizes, int n_in,
                              void* d_out, int out_size, void* d_ws, size_t ws_size,
                              hipStream_t stream) {
    const int*   rows = (const int*)d_in[0];
    const int*   cols = (const int*)d_in[1];
    const float* vals = (const float*)d_in[2];
    const float* x    = (const float*)d_in[3];
    float*       out  = (float*)d_out;
    const int nnz = in_sizes[0];

    const size_t WF_BYTES = (size_t)GM * GK * 4;   // 64 MB fp32 W (later reused for xT)
    const size_t WB_BYTES = (size_t)GM * GK * 2;   // 32 MB bf16 W
    const size_t NEED = WF_BYTES + WB_BYTES;       // 96 MB

    if (ws_size >= NEED) {
        float*          Wf = (float*)d_ws;
        unsigned short* Wb = (unsigned short*)((char*)d_ws + WF_BYTES);
        unsigned short* xT = (unsigned short*)d_ws;  // reuses Wf region after convert_w

        hipMemsetAsync(Wf, 0, WF_BYTES, stream);
        scatter_dense<<<(nnz + 255) / 256, 256, 0, stream>>>(rows, cols, vals, Wf, nnz);
        convert_w<<<(GM * GK / 4) / 256, 256, 0, stream>>>(Wf, Wb);
        // Wf is dead now; overwrite its region with xT
        dim3 tg(GK / 64, GN / 64);
        transpose_x<<<tg, 256, 0, stream>>>(x, xT);
        dim3 gg(GN / 256, GM / 256);
        gemm256<<<gg, 512, 0, stream>>>(Wb, xT, out);
    } else {
        // fallback: CSR SpMM (round-1 path)
        int*   ws_i    = (int*)d_ws;
        int*   counts  = ws_i + WS_COUNTS;
        int*   offsets = ws_i + WS_OFFSETS;
        int*   cursor  = ws_i + WS_CURSOR;
        int*   cols_s  = ws_i + WS_HEADER;
        float* vals_s  = (float*)(ws_i + WS_HEADER + nnz);

        hipMemsetAsync(d_ws, 0, (size_t)WS_HEADER * sizeof(int), stream);
        const int nblk = (nnz + 255) / 256;
        hist_kernel<<<nblk, 256, 0, stream>>>(rows, counts, nnz);
        scan_kernel<<<1, 256, 0, stream>>>(counts, offsets);
        scatter_kernel<<<nblk, 256, 0, stream>>>(rows, cols, vals, offsets, cursor,
                                                 cols_s, vals_s, nnz);
        dim3 grid(OUT_F, NCOLS / 1024);
        spmm_kernel<<<grid, 256, 0, stream>>>(offsets, cols_s, vals_s, x, out);
    }
}

// Round 2
// 541.048 us; speedup vs baseline: 1.0482x; 1.0122x over previous
//
#include <hip/hip_runtime.h>

// Problem constants (match reference)
#define OUT_F 4096   // M
#define IN_F  4096   // K
#define NCOLS 8192   // N

#define GM OUT_F
#define GK IN_F
#define GN NCOLS

typedef __attribute__((ext_vector_type(8))) short short8;
typedef __attribute__((ext_vector_type(4))) float f32x4;

// ---------------------------------------------------------------------------
// helpers
// ---------------------------------------------------------------------------
__device__ inline unsigned short f2bf(float f) {
    union { float f; unsigned u; } c; c.f = f;
    unsigned u = c.u;
    u += 0x7fffu + ((u >> 16) & 1u);   // round-to-nearest-even
    return (unsigned short)(u >> 16);
}

__device__ inline void gll16(const void* g, void* l) {
    __builtin_amdgcn_global_load_lds(
        (const __attribute__((address_space(1))) unsigned int*)g,
        (__attribute__((address_space(3))) unsigned int*)l, 16, 0, 0);
}

// ---------------------------------------------------------------------------
// Densify path
// ---------------------------------------------------------------------------
__global__ void scatter_dense(const int* __restrict__ rows, const int* __restrict__ cols,
                              const float* __restrict__ vals, float* __restrict__ W, int nnz) {
    int i = blockIdx.x * blockDim.x + threadIdx.x;
    if (i < nnz) atomicAdd(&W[(size_t)rows[i] * IN_F + cols[i]], vals[i]);
}

__global__ void convert_w(const float* __restrict__ Wf, unsigned short* __restrict__ Wb) {
    int i = blockIdx.x * blockDim.x + threadIdx.x;  // over elems/4
    float4 v = ((const float4*)Wf)[i];
    ushort4 o;
    o.x = f2bf(v.x); o.y = f2bf(v.y); o.z = f2bf(v.z); o.w = f2bf(v.w);
    ((ushort4*)Wb)[i] = o;
}

// x [IN_F][NCOLS] f32 -> xT [NCOLS][IN_F] bf16, 64x64 tiles via LDS
__global__ __launch_bounds__(256) void transpose_x(const float* __restrict__ x,
                                                   unsigned short* __restrict__ xT) {
    __shared__ float tile[64][65];
    const int k0 = blockIdx.x * 64;   // x row block (K dim)
    const int n0 = blockIdx.y * 64;   // x col block (N dim)
    const int t = threadIdx.x;
    const int c4 = (t & 15) * 4;
    const int r0 = t >> 4;            // 0..15
    for (int p = 0; p < 4; ++p) {
        int r = r0 + p * 16;
        float4 v = *(const float4*)&x[(size_t)(k0 + r) * NCOLS + n0 + c4];
        tile[r][c4 + 0] = v.x; tile[r][c4 + 1] = v.y;
        tile[r][c4 + 2] = v.z; tile[r][c4 + 3] = v.w;
    }
    __syncthreads();
    const int n  = t >> 2;            // 0..63
    const int ks = (t & 3) * 16;      // 0,16,32,48
    unsigned w[8];
    for (int m = 0; m < 8; ++m) {
        unsigned short lo = f2bf(tile[ks + 2 * m + 0][n]);
        unsigned short hi = f2bf(tile[ks + 2 * m + 1][n]);
        w[m] = (unsigned)lo | ((unsigned)hi << 16);
    }
    uint4* dst = (uint4*)&xT[(size_t)(n0 + n) * GK + k0 + ks];
    dst[0] = make_uint4(w[0], w[1], w[2], w[3]);
    dst[1] = make_uint4(w[4], w[5], w[6], w[7]);
}

// ---------------------------------------------------------------------------
// GEMM: C[GM][GN] f32 = A(bf16 [GM][GK]) * B, with B given as BT bf16 [GN][GK].
// 256x256 8-phase schedule (T1+T2+T3+T4+T5, guide §5 template):
//   512 thr = 8 waves (2M x 4N), per-wave output 128x64, BK=64 (2 K-halves of 32).
//   LDS = 8 half-slots of 16 KiB: [buf(2)][op(2)][khalf(2)] x (256 rows x 32k bf16).
//   Per phase: {4-or-8 ds_read_b128 | stage 1 half-slot (2x global_load_lds w16) |
//               s_barrier | setprio(1) 16x MFMA setprio(0) | [vmcnt(8)] s_barrier}.
//   vmcnt(8) only at even phase ends: 6 half-slots (12 loads) max outstanding,
//   each wait retires the 2 oldest half-slots = exactly what the next odd phase reads.
//
//   Swizzle (R2 fix): 64B row of 4x16B slots. Bank-group of a 16B access is
//   g = (row&1)<<2 | slot  (byte = row*64 + slot*16 -> bits[6:4]).
//   R1 used slot = jhi ^ (frow&3): slot&1 correlated with row&1 -> within a
//   16-lane quarter only 4/8 groups hit = 4-way conflict (2.5e7 measured).
//   Now: logical k-block j of row r lives at slot j ^ ((r>>1)&3). For fixed jhi,
//   frow=0..15 covers all 8 groups exactly 2x (2-way = free, m136).
//   Stage pre-swizzles the GLOBAL source (LDS dest stays linear, rule #21);
//   the 4 lanes of a row still cover one permuted 64B segment -> coalescing kept.
// ---------------------------------------------------------------------------
__global__ __launch_bounds__(512, 2) void gemm256(const unsigned short* __restrict__ A,
                                                  const unsigned short* __restrict__ BT,
                                                  float* __restrict__ C) {
    __shared__ unsigned short lds[8 * 8192];   // 128 KiB

    const int tid  = threadIdx.x;
    const int wave = tid >> 6;
    const int lane = tid & 63;

    // XCD-aware bijective swizzle (nwg = 512, 512 % 8 == 0)
    const int wg  = blockIdx.y * 32 + blockIdx.x;
    const int swz = (wg & 7) * 64 + (wg >> 3);
    const int m0  = (swz >> 5) * 256;
    const int n0  = (swz & 31) * 256;

    const int wm = wave >> 2;          // 0..1  (M half of tile)
    const int wn = wave & 3;           // 0..3  (N quarter of tile)

    // staging mapping: chunk c = q*512 + tid; row r = c>>2 (0..255), slot s = c&3.
    // lane fetches global k-block s^((r>>1)&3) so linear LDS slot s holds swizzled data.
    const int r0s  = tid >> 2;                              // 0..127 (q=0), +128 for q=1
    const int swz0 = ((tid & 3) ^ ((r0s >> 1) & 3)) << 3;   // elems
    const unsigned short* pA0 = A  + (size_t)(m0 + r0s) * GK + swz0;
    const unsigned short* pA1 = pA0 + (size_t)128 * GK;
    const unsigned short* pB0 = BT + (size_t)(n0 + r0s) * GK + swz0;
    const unsigned short* pB1 = pB0 + (size_t)128 * GK;

    // fragment mapping for 16x16x32: row = 16*frag + frow, k-block = lane>>4
    // row>>1 & 3 == frow>>1 & 3 (16*frag, 128*wm, +128 are all = 0 mod 4 after >>1... 
    // precisely: those terms are multiples of 8 in (row>>1) space -> drop under &3)
    const int frow  = lane & 15;
    const int ajb   = ((lane >> 4) ^ ((frow >> 1) & 3)) << 3;   // swizzled 8-elem block
    const int abase = ((wm << 7) + frow) * 32 + ajb;            // A region elem offset
    const int bbase = ((wn << 6) + frow) * 32 + ajb;            // B region elem offset

    f32x4 acc[8][4] = {};

#define STAGE_A(bufc, khc, kt_) do {                                            \
        const int koA_ = ((((kt_) & 63) << 6) + ((khc) << 5));                  \
        gll16(pA0 + koA_, &lds[(((bufc) << 2) + (khc)) * 8192 + (wave << 9)]);  \
        gll16(pA1 + koA_, &lds[(((bufc) << 2) + (khc)) * 8192 + 4096 + (wave << 9)]); \
    } while (0)

#define STAGE_B(bufc, khc, kt_) do {                                            \
        const int koB_ = ((((kt_) & 63) << 6) + ((khc) << 5));                  \
        gll16(pB0 + koB_, &lds[(((bufc) << 2) + 2 + (khc)) * 8192 + (wave << 9)]); \
        gll16(pB1 + koB_, &lds[(((bufc) << 2) + 2 + (khc)) * 8192 + 4096 + (wave << 9)]); \
    } while (0)

    // prologue: stage kt0 fully + kt1 khalf0  (= steady-state S3..S8 pattern)
    STAGE_A(0, 0, 0); STAGE_B(0, 0, 0);
    STAGE_A(0, 1, 0); STAGE_B(0, 1, 0);
    STAGE_A(1, 0, 1); STAGE_B(1, 0, 1);
    asm volatile("s_waitcnt vmcnt(8)" ::: "memory");   // oldest 2 half-slots resident
    __builtin_amdgcn_s_barrier();

// One K-half = 2 phases (mh0, mh1). bf reused across both (8/4 ds_read pattern).
// vmcnt(8) at the pair end retires the 2 oldest in-flight half-slots.
#define KHALF_BLOCK(bufc, khc, STAGE1, STAGE2) do {                             \
        const unsigned short* Ar_ = &lds[(((bufc) << 2) + (khc)) * 8192];       \
        const unsigned short* Br_ = &lds[(((bufc) << 2) + 2 + (khc)) * 8192];   \
        short8 af[4], bf[4];                                                    \
        _Pragma("unroll")                                                       \
        for (int nj = 0; nj < 4; ++nj) bf[nj] = *(const short8*)&Br_[bbase + nj * 512]; \
        _Pragma("unroll")                                                       \
        for (int mi = 0; mi < 4; ++mi) af[mi] = *(const short8*)&Ar_[abase + mi * 512]; \
        STAGE1;                                                                 \
        __builtin_amdgcn_s_barrier();                                           \
        __builtin_amdgcn_s_setprio(1);                                          \
        _Pragma("unroll")                                                       \
        for (int mi = 0; mi < 4; ++mi)                                          \
            _Pragma("unroll")                                                   \
            for (int nj = 0; nj < 4; ++nj)                                      \
                acc[mi][nj] = __builtin_amdgcn_mfma_f32_16x16x32_bf16(          \
                    af[mi], bf[nj], acc[mi][nj], 0, 0, 0);                      \
        __builtin_amdgcn_s_setprio(0);                                          \
        __builtin_amdgcn_s_barrier();                                           \
        _Pragma("unroll")                                                       \
        for (int mi = 0; mi < 4; ++mi) af[mi] = *(const short8*)&Ar_[abase + (4 + mi) * 512]; \
        STAGE2;                                                                 \
        __builtin_amdgcn_s_barrier();                                           \
        __builtin_amdgcn_s_setprio(1);                                          \
        _Pragma("unroll")                                                       \
        for (int mi = 0; mi < 4; ++mi)                                          \
            _Pragma("unroll")                                                   \
            for (int nj = 0; nj < 4; ++nj)                                      \
                acc[4 + mi][nj] = __builtin_amdgcn_mfma_f32_16x16x32_bf16(      \
                    af[mi], bf[nj], acc[4 + mi][nj], 0, 0, 0);                  \
        __builtin_amdgcn_s_setprio(0);                                          \
        asm volatile("s_waitcnt vmcnt(8)" ::: "memory");                        \
        __builtin_amdgcn_s_barrier();                                           \
    } while (0)

#pragma unroll 1
    for (int it = 0; it < GK / 128; ++it) {
        const int kt = it * 2;
        // P1/P2: compute buf0.kh0, stage buf1.kh1 <- kt+1 (freed prev P7/P8)
        KHALF_BLOCK(0, 0, STAGE_A(1, 1, kt + 1), STAGE_B(1, 1, kt + 1));
        // P3/P4: compute buf0.kh1, stage buf0.kh0 <- kt+2 (freed at P2)
        KHALF_BLOCK(0, 1, STAGE_A(0, 0, kt + 2), STAGE_B(0, 0, kt + 2));
        // P5/P6: compute buf1.kh0, stage buf0.kh1 <- kt+2 (freed at P4)
        KHALF_BLOCK(1, 0, STAGE_A(0, 1, kt + 2), STAGE_B(0, 1, kt + 2));
        // P7/P8: compute buf1.kh1, stage buf1.kh0 <- kt+3 (freed at P6)
        KHALF_BLOCK(1, 1, STAGE_A(1, 0, kt + 3), STAGE_B(1, 0, kt + 3));
    }
#undef KHALF_BLOCK
#undef STAGE_A
#undef STAGE_B

    // epilogue: C/D layout col=lane&15, row=(lane>>4)*4+reg
    for (int mi = 0; mi < 8; ++mi) {
        const int r0w = m0 + wm * 128 + mi * 16 + (lane >> 4) * 4;
        for (int nj = 0; nj < 4; ++nj) {
            const int cc = n0 + wn * 64 + nj * 16 + frow;
            for (int r = 0; r < 4; ++r)
                C[(size_t)(r0w + r) * GN + cc] = acc[mi][nj][r];
        }
    }
}

// ---------------------------------------------------------------------------
// Fallback SpMM path (round-1 kernel) if workspace is too small for densify
// ---------------------------------------------------------------------------
#define WS_COUNTS  0
#define WS_OFFSETS 4097
#define WS_CURSOR  8194
#define WS_HEADER  12290

__global__ void hist_kernel(const int* __restrict__ rows, int* __restrict__ counts, int nnz) {
    int i = blockIdx.x * blockDim.x + threadIdx.x;
    if (i < nnz) atomicAdd(&counts[rows[i]], 1);
}

__global__ void scan_kernel(const int* __restrict__ counts, int* __restrict__ offsets) {
    __shared__ int lsum[256];
    int t = threadIdx.x;
    int base = t * 16;
    int local[16];
    int s = 0;
    for (int i = 0; i < 16; ++i) { local[i] = counts[base + i]; s += local[i]; }
    lsum[t] = s;
    __syncthreads();
    if (t == 0) {
        int acc = 0;
        for (int i = 0; i < 256; ++i) { int v = lsum[i]; lsum[i] = acc; acc += v; }
        offsets[OUT_F] = acc;
    }
    __syncthreads();
    int acc = lsum[t];
    for (int i = 0; i < 16; ++i) { offsets[base + i] = acc; acc += local[i]; }
}

__global__ void scatter_kernel(const int* __restrict__ rows, const int* __restrict__ cols,
                               const float* __restrict__ vals,
                               const int* __restrict__ offsets, int* __restrict__ cursor,
                               int* __restrict__ cols_s, float* __restrict__ vals_s, int nnz) {
    int i = blockIdx.x * blockDim.x + threadIdx.x;
    if (i < nnz) {
        int r = rows[i];
        int pos = offsets[r] + atomicAdd(&cursor[r], 1);
        cols_s[pos] = cols[i];
        vals_s[pos] = vals[i];
    }
}

__global__ __launch_bounds__(256) void spmm_kernel(const int* __restrict__ offsets,
                                                   const int* __restrict__ cols_s,
                                                   const float* __restrict__ vals_s,
                                                   const float* __restrict__ x,
                                                   float* __restrict__ out) {
    const int row  = blockIdx.x;
    const int col0 = blockIdx.y * 1024 + threadIdx.x * 4;
    const int k0 = offsets[row];
    const int k1 = offsets[row + 1];
    float4 acc = make_float4(0.f, 0.f, 0.f, 0.f);
    for (int k = k0; k < k1; ++k) {
        const int   c = cols_s[k];
        const float v = vals_s[k];
        const float4 xv = *reinterpret_cast<const float4*>(x + (size_t)c * NCOLS + col0);
        acc.x += v * xv.x;
        acc.y += v * xv.y;
        acc.z += v * xv.z;
        acc.w += v * xv.w;
    }
    *reinterpret_cast<float4*>(out + (size_t)row * NCOLS + col0) = acc;
}

// ---------------------------------------------------------------------------
extern "C" void kernel_launch(void* const* d_in, const int* in_sizes, int n_in,
                              void* d_out, int out_size, void* d_ws, size_t ws_size,
                              hipStream_t stream) {
    const int*   rows = (const int*)d_in[0];
    const int*   cols = (const int*)d_in[1];
    const float* vals = (const float*)d_in[2];
    const float* x    = (const float*)d_in[3];
    float*       out  = (float*)d_out;
    const int nnz = in_sizes[0];

    const size_t WF_BYTES = (size_t)GM * GK * 4;   // 64 MB fp32 W (later reused for xT)
    const size_t WB_BYTES = (size_t)GM * GK * 2;   // 32 MB bf16 W
    const size_t NEED = WF_BYTES + WB_BYTES;       // 96 MB

    if (ws_size >= NEED) {
        float*          Wf = (float*)d_ws;
        unsigned short* Wb = (unsigned short*)((char*)d_ws + WF_BYTES);
        unsigned short* xT = (unsigned short*)d_ws;  // reuses Wf region after convert_w

        hipMemsetAsync(Wf, 0, WF_BYTES, stream);
        scatter_dense<<<(nnz + 255) / 256, 256, 0, stream>>>(rows, cols, vals, Wf, nnz);
        convert_w<<<(GM * GK / 4) / 256, 256, 0, stream>>>(Wf, Wb);
        // Wf is dead now; overwrite its region with xT
        dim3 tg(GK / 64, GN / 64);
        transpose_x<<<tg, 256, 0, stream>>>(x, xT);
        dim3 gg(GN / 256, GM / 256);
        gemm256<<<gg, 512, 0, stream>>>(Wb, xT, out);
    } else {
        // fallback: CSR SpMM (round-1 path)
        int*   ws_i    = (int*)d_ws;
        int*   counts  = ws_i + WS_COUNTS;
        int*   offsets = ws_i + WS_OFFSETS;
        int*   cursor  = ws_i + WS_CURSOR;
        int*   cols_s  = ws_i + WS_HEADER;
        float* vals_s  = (float*)(ws_i + WS_HEADER + nnz);

        hipMemsetAsync(d_ws, 0, (size_t)WS_HEADER * sizeof(int), stream);
        const int nblk = (nnz + 255) / 256;
        hist_kernel<<<nblk, 256, 0, stream>>>(rows, counts, nnz);
        scan_kernel<<<1, 256, 0, stream>>>(counts, offsets);
        scatter_kernel<<<nblk, 256, 0, stream>>>(rows, cols, vals, offsets, cursor,
                                                 cols_s, vals_s, nnz);
        dim3 grid(OUT_F, NCOLS / 1024);
        spmm_kernel<<<grid, 256, 0, stream>>>(offsets, cols_s, vals_s, x, out);
    }
}

// Round 3
// 527.318 us; speedup vs baseline: 1.0755x; 1.0260x over previous
//
#include <hip/hip_runtime.h>

// Problem constants (match reference)
#define OUT_F 4096   // M
#define IN_F  4096   // K
#define NCOLS 8192   // N

#define GM OUT_F
#define GK IN_F
#define GN NCOLS

typedef __attribute__((ext_vector_type(8))) short short8;
typedef __attribute__((ext_vector_type(4))) float f32x4;

// ---------------------------------------------------------------------------
// helpers
// ---------------------------------------------------------------------------
__device__ inline unsigned short f2bf(float f) {
    union { float f; unsigned u; } c; c.f = f;
    unsigned u = c.u;
    u += 0x7fffu + ((u >> 16) & 1u);   // round-to-nearest-even
    return (unsigned short)(u >> 16);
}

__device__ inline void gll16(const void* g, void* l) {
    __builtin_amdgcn_global_load_lds(
        (const __attribute__((address_space(1))) unsigned int*)g,
        (__attribute__((address_space(3))) unsigned int*)l, 16, 0, 0);
}

// ---------------------------------------------------------------------------
// Densify path
// ---------------------------------------------------------------------------
__global__ void scatter_dense(const int* __restrict__ rows, const int* __restrict__ cols,
                              const float* __restrict__ vals, float* __restrict__ W, int nnz) {
    int i = blockIdx.x * blockDim.x + threadIdx.x;
    if (i < nnz) atomicAdd(&W[(size_t)rows[i] * IN_F + cols[i]], vals[i]);
}

__global__ void convert_w(const float* __restrict__ Wf, unsigned short* __restrict__ Wb) {
    int i = blockIdx.x * blockDim.x + threadIdx.x;  // over elems/4
    float4 v = ((const float4*)Wf)[i];
    ushort4 o;
    o.x = f2bf(v.x); o.y = f2bf(v.y); o.z = f2bf(v.z); o.w = f2bf(v.w);
    ((ushort4*)Wb)[i] = o;
}

// x [IN_F][NCOLS] f32 -> xT [NCOLS][IN_F] bf16, 64x64 tiles via LDS
__global__ __launch_bounds__(256) void transpose_x(const float* __restrict__ x,
                                                   unsigned short* __restrict__ xT) {
    __shared__ float tile[64][65];
    const int k0 = blockIdx.x * 64;   // x row block (K dim)
    const int n0 = blockIdx.y * 64;   // x col block (N dim)
    const int t = threadIdx.x;
    const int c4 = (t & 15) * 4;
    const int r0 = t >> 4;            // 0..15
    for (int p = 0; p < 4; ++p) {
        int r = r0 + p * 16;
        float4 v = *(const float4*)&x[(size_t)(k0 + r) * NCOLS + n0 + c4];
        tile[r][c4 + 0] = v.x; tile[r][c4 + 1] = v.y;
        tile[r][c4 + 2] = v.z; tile[r][c4 + 3] = v.w;
    }
    __syncthreads();
    const int n  = t >> 2;            // 0..63
    const int ks = (t & 3) * 16;      // 0,16,32,48
    unsigned w[8];
    for (int m = 0; m < 8; ++m) {
        unsigned short lo = f2bf(tile[ks + 2 * m + 0][n]);
        unsigned short hi = f2bf(tile[ks + 2 * m + 1][n]);
        w[m] = (unsigned)lo | ((unsigned)hi << 16);
    }
    uint4* dst = (uint4*)&xT[(size_t)(n0 + n) * GK + k0 + ks];
    dst[0] = make_uint4(w[0], w[1], w[2], w[3]);
    dst[1] = make_uint4(w[4], w[5], w[6], w[7]);
}

// ---------------------------------------------------------------------------
// GEMM: C[GM][GN] f32 = A(bf16 [GM][GK]) * B, with B given as BT bf16 [GN][GK].
// R3: rolling 1-barrier-per-phase pipeline.
//   512 thr = 8 waves (2M x 4N), per-wave output 128x64.
//   LDS = 4 rotating slots, each = A(256rows x 32k) + B(256rows x 32k) bf16 = 32 KiB.
//   Phase p (K=32, 32 MFMA/wave):
//     s_waitcnt vmcnt(4)   // retires stages of slot p+1 (issued at phase p-2)
//     s_barrier            // cross-wave residency + WAR fence (asm, no implicit drain)
//     ds_read af2 (slot p, rows 64..127) + bf/af1 (slot p+1)   // 12 ds_read_b128
//     stage slot p+3 (4 x global_load_lds w16)
//     setprio(1); 32 MFMA (af1 x bf -> acc[0..3], af2 x bf -> acc[4..7]); setprio(0)
//   All lgkm waits are covered: next-phase frags issued one phase early; af2 hides
//   under the first 16-MFMA burst. vmcnt never drains below 4 (2 slots in flight).
//   Hazards: slots {p, p+1, p+3} distinct mod 4; stage@p writes region of slot p-1
//   whose reads drained before each wave's MFMA issue at p-1 (precedes barrier@p).
//   Swizzle (unchanged from R2, conflict-free): 64B row of 4x16B slots; logical
//   k-block j of row r lives at slot j ^ ((r>>1)&3); staged via pre-swizzled
//   global source (rule #21), read back with the same involution.
// ---------------------------------------------------------------------------
__global__ __launch_bounds__(512, 2) void gemm256(const unsigned short* __restrict__ A,
                                                  const unsigned short* __restrict__ BT,
                                                  float* __restrict__ C) {
    __shared__ unsigned short lds[65536];   // 128 KiB: A slots [0,32768), B slots [32768,65536)

    const int tid  = threadIdx.x;
    const int wave = tid >> 6;
    const int lane = tid & 63;

    // XCD-aware bijective swizzle (nwg = 512, 512 % 8 == 0)
    const int wg  = blockIdx.y * 32 + blockIdx.x;
    const int swz = (wg & 7) * 64 + (wg >> 3);
    const int m0  = (swz >> 5) * 256;
    const int n0  = (swz & 31) * 256;

    const int wm = wave >> 2;          // 0..1  (M half of tile)
    const int wn = wave & 3;           // 0..3  (N quarter of tile)

    // staging mapping: chunk c = q*512 + tid; row r = c>>2 (0..255), slot s = c&3.
    // lane fetches global k-block s^((r>>1)&3) so linear LDS slot s holds swizzled data.
    const int r0s  = tid >> 2;                              // 0..127 (q=0), +128 for q=1
    const int swz0 = ((tid & 3) ^ ((r0s >> 1) & 3)) << 3;   // elems
    const unsigned short* pA0 = A  + (size_t)(m0 + r0s) * GK + swz0;
    const unsigned short* pA1 = pA0 + (size_t)128 * GK;
    const unsigned short* pB0 = BT + (size_t)(n0 + r0s) * GK + swz0;
    const unsigned short* pB1 = pB0 + (size_t)128 * GK;

    // fragment mapping for 16x16x32: row = 16*frag + frow, k-block = lane>>4
    const int frow  = lane & 15;
    const int ajb   = ((lane >> 4) ^ ((frow >> 1) & 3)) << 3;   // swizzled 8-elem block
    const int abase = ((wm << 7) + frow) * 32 + ajb;            // A region elem offset
    const int bbase = ((wn << 6) + frow) * 32 + ajb;            // B region elem offset

    f32x4 acc[8][4] = {};

    // stage slot s_ with data for phase q_ (global k = 32*q_)
#define STAGE(q_, s_) do {                                              \
        const int ko_ = (((q_) & 127) << 5);                            \
        gll16(pA0 + ko_, &lds[(s_) * 8192 + (wave << 9)]);              \
        gll16(pA1 + ko_, &lds[(s_) * 8192 + 4096 + (wave << 9)]);       \
        gll16(pB0 + ko_, &lds[32768 + (s_) * 8192 + (wave << 9)]);      \
        gll16(pB1 + ko_, &lds[32768 + (s_) * 8192 + 4096 + (wave << 9)]); \
    } while (0)

    // prologue: slots 0,1,2 staged; slot 0 resident; phase-0 frags in flight
    STAGE(0, 0); STAGE(1, 1); STAGE(2, 2);
    asm volatile("s_waitcnt vmcnt(8)" ::: "memory");   // slot 0 resident
    asm volatile("s_barrier" ::: "memory");

    short8 bfX[4], afX[4], bfY[4], afY[4];
    {
        const unsigned short* Ar0 = &lds[0];
        const unsigned short* Br0 = &lds[32768];
#pragma unroll
        for (int nj = 0; nj < 4; ++nj) bfX[nj] = *(const short8*)&Br0[bbase + nj * 512];
#pragma unroll
        for (int mi = 0; mi < 4; ++mi) afX[mi] = *(const short8*)&Ar0[abase + mi * 512];
    }

// one phase: e_ = p&3 (compile-time), bfC/afC = current set, bfN/afN = next set
#define PHASE(e_, bfC, afC, bfN, afN, jj) do {                                  \
        asm volatile("s_waitcnt vmcnt(4)" ::: "memory");                        \
        asm volatile("s_barrier" ::: "memory");                                 \
        const unsigned short* ArC = &lds[(e_) * 8192];                          \
        const unsigned short* ArN = &lds[(((e_) + 1) & 3) * 8192];              \
        const unsigned short* BrN = &lds[32768 + (((e_) + 1) & 3) * 8192];      \
        short8 af2[4];                                                          \
        _Pragma("unroll")                                                       \
        for (int mi = 0; mi < 4; ++mi)                                          \
            af2[mi] = *(const short8*)&ArC[abase + (4 + mi) * 512];             \
        _Pragma("unroll")                                                       \
        for (int nj = 0; nj < 4; ++nj)                                          \
            bfN[nj] = *(const short8*)&BrN[bbase + nj * 512];                   \
        _Pragma("unroll")                                                       \
        for (int mi = 0; mi < 4; ++mi)                                          \
            afN[mi] = *(const short8*)&ArN[abase + mi * 512];                   \
        STAGE(4 * (jj) + (e_) + 3, ((e_) + 3) & 3);                             \
        __builtin_amdgcn_s_setprio(1);                                          \
        _Pragma("unroll")                                                       \
        for (int mi = 0; mi < 4; ++mi)                                          \
            _Pragma("unroll")                                                   \
            for (int nj = 0; nj < 4; ++nj)                                      \
                acc[mi][nj] = __builtin_amdgcn_mfma_f32_16x16x32_bf16(          \
                    afC[mi], bfC[nj], acc[mi][nj], 0, 0, 0);                    \
        _Pragma("unroll")                                                       \
        for (int mi = 0; mi < 4; ++mi)                                          \
            _Pragma("unroll")                                                   \
            for (int nj = 0; nj < 4; ++nj)                                      \
                acc[4 + mi][nj] = __builtin_amdgcn_mfma_f32_16x16x32_bf16(      \
                    af2[mi], bfC[nj], acc[4 + mi][nj], 0, 0, 0);                \
        __builtin_amdgcn_s_setprio(0);                                          \
    } while (0)

#pragma unroll 1
    for (int j = 0; j < GK / 128; ++j) {   // 32 iters x 4 phases = 128 phases (K=32 each)
        PHASE(0, bfX, afX, bfY, afY, j);
        PHASE(1, bfY, afY, bfX, afX, j);
        PHASE(2, bfX, afX, bfY, afY, j);
        PHASE(3, bfY, afY, bfX, afX, j);
    }
#undef PHASE
#undef STAGE

    // epilogue: C/D layout col=lane&15, row=(lane>>4)*4+reg
    for (int mi = 0; mi < 8; ++mi) {
        const int r0w = m0 + wm * 128 + mi * 16 + (lane >> 4) * 4;
        for (int nj = 0; nj < 4; ++nj) {
            const int cc = n0 + wn * 64 + nj * 16 + frow;
            for (int r = 0; r < 4; ++r)
                C[(size_t)(r0w + r) * GN + cc] = acc[mi][nj][r];
        }
    }
}

// ---------------------------------------------------------------------------
// Fallback SpMM path (round-1 kernel) if workspace is too small for densify
// ---------------------------------------------------------------------------
#define WS_COUNTS  0
#define WS_OFFSETS 4097
#define WS_CURSOR  8194
#define WS_HEADER  12290

__global__ void hist_kernel(const int* __restrict__ rows, int* __restrict__ counts, int nnz) {
    int i = blockIdx.x * blockDim.x + threadIdx.x;
    if (i < nnz) atomicAdd(&counts[rows[i]], 1);
}

__global__ void scan_kernel(const int* __restrict__ counts, int* __restrict__ offsets) {
    __shared__ int lsum[256];
    int t = threadIdx.x;
    int base = t * 16;
    int local[16];
    int s = 0;
    for (int i = 0; i < 16; ++i) { local[i] = counts[base + i]; s += local[i]; }
    lsum[t] = s;
    __syncthreads();
    if (t == 0) {
        int acc = 0;
        for (int i = 0; i < 256; ++i) { int v = lsum[i]; lsum[i] = acc; acc += v; }
        offsets[OUT_F] = acc;
    }
    __syncthreads();
    int acc = lsum[t];
    for (int i = 0; i < 16; ++i) { offsets[base + i] = acc; acc += local[i]; }
}

__global__ void scatter_kernel(const int* __restrict__ rows, const int* __restrict__ cols,
                               const float* __restrict__ vals,
                               const int* __restrict__ offsets, int* __restrict__ cursor,
                               int* __restrict__ cols_s, float* __restrict__ vals_s, int nnz) {
    int i = blockIdx.x * blockDim.x + threadIdx.x;
    if (i < nnz) {
        int r = rows[i];
        int pos = offsets[r] + atomicAdd(&cursor[r], 1);
        cols_s[pos] = cols[i];
        vals_s[pos] = vals[i];
    }
}

__global__ __launch_bounds__(256) void spmm_kernel(const int* __restrict__ offsets,
                                                   const int* __restrict__ cols_s,
                                                   const float* __restrict__ vals_s,
                                                   const float* __restrict__ x,
                                                   float* __restrict__ out) {
    const int row  = blockIdx.x;
    const int col0 = blockIdx.y * 1024 + threadIdx.x * 4;
    const int k0 = offsets[row];
    const int k1 = offsets[row + 1];
    float4 acc = make_float4(0.f, 0.f, 0.f, 0.f);
    for (int k = k0; k < k1; ++k) {
        const int   c = cols_s[k];
        const float v = vals_s[k];
        const float4 xv = *reinterpret_cast<const float4*>(x + (size_t)c * NCOLS + col0);
        acc.x += v * xv.x;
        acc.y += v * xv.y;
        acc.z += v * xv.z;
        acc.w += v * xv.w;
    }
    *reinterpret_cast<float4*>(out + (size_t)row * NCOLS + col0) = acc;
}

// ---------------------------------------------------------------------------
extern "C" void kernel_launch(void* const* d_in, const int* in_sizes, int n_in,
                              void* d_out, int out_size, void* d_ws, size_t ws_size,
                              hipStream_t stream) {
    const int*   rows = (const int*)d_in[0];
    const int*   cols = (const int*)d_in[1];
    const float* vals = (const float*)d_in[2];
    const float* x    = (const float*)d_in[3];
    float*       out  = (float*)d_out;
    const int nnz = in_sizes[0];

    const size_t WF_BYTES = (size_t)GM * GK * 4;   // 64 MB fp32 W (later reused for xT)
    const size_t WB_BYTES = (size_t)GM * GK * 2;   // 32 MB bf16 W
    const size_t NEED = WF_BYTES + WB_BYTES;       // 96 MB

    if (ws_size >= NEED) {
        float*          Wf = (float*)d_ws;
        unsigned short* Wb = (unsigned short*)((char*)d_ws + WF_BYTES);
        unsigned short* xT = (unsigned short*)d_ws;  // reuses Wf region after convert_w

        hipMemsetAsync(Wf, 0, WF_BYTES, stream);
        scatter_dense<<<(nnz + 255) / 256, 256, 0, stream>>>(rows, cols, vals, Wf, nnz);
        convert_w<<<(GM * GK / 4) / 256, 256, 0, stream>>>(Wf, Wb);
        // Wf is dead now; overwrite its region with xT
        dim3 tg(GK / 64, GN / 64);
        transpose_x<<<tg, 256, 0, stream>>>(x, xT);
        dim3 gg(GN / 256, GM / 256);
        gemm256<<<gg, 512, 0, stream>>>(Wb, xT, out);
    } else {
        // fallback: CSR SpMM (round-1 path)
        int*   ws_i    = (int*)d_ws;
        int*   counts  = ws_i + WS_COUNTS;
        int*   offsets = ws_i + WS_OFFSETS;
        int*   cursor  = ws_i + WS_CURSOR;
        int*   cols_s  = ws_i + WS_HEADER;
        float* vals_s  = (float*)(ws_i + WS_HEADER + nnz);

        hipMemsetAsync(d_ws, 0, (size_t)WS_HEADER * sizeof(int), stream);
        const int nblk = (nnz + 255) / 256;
        hist_kernel<<<nblk, 256, 0, stream>>>(rows, counts, nnz);
        scan_kernel<<<1, 256, 0, stream>>>(counts, offsets);
        scatter_kernel<<<nblk, 256, 0, stream>>>(rows, cols, vals, offsets, cursor,
                                                 cols_s, vals_s, nnz);
        dim3 grid(OUT_F, NCOLS / 1024);
        spmm_kernel<<<grid, 256, 0, stream>>>(offsets, cols_s, vals_s, x, out);
    }
}